// Round 2
// baseline (211.545 us; speedup 1.0000x reference)
//
#include <hip/hip_runtime.h>

#define N_    16
#define CIN_  64
#define HW_   56
#define COUT_ 64
#define HP    58            // padded H/W
#define HPSQ  (HP * HP)     // 3364

typedef float f4u __attribute__((ext_vector_type(4), aligned(4)));  // dword-aligned vec load

// ---- kernel 1: zero-padded copy of x into ws: xp[n][ci][58][58] ----
__global__ void pad_x_kernel(const float* __restrict__ x, float* __restrict__ xp) {
    int idx = blockIdx.x * 256 + threadIdx.x;
    const int total = N_ * CIN_ * HPSQ;
    if (idx >= total) return;
    int w  = idx % HP;
    int t  = idx / HP;
    int h  = t % HP;
    int nc = t / HP;
    float v = 0.f;
    if (h >= 1 && h <= HW_ && w >= 1 && w <= HW_)
        v = x[((size_t)nc * HW_ + (h - 1)) * HW_ + (w - 1)];
    xp[idx] = v;
}

// ---- main kernel helpers ----
__device__ __forceinline__ void load_tile(const float* __restrict__ xc,
                                          float (&buf)[9][9]) {
    #pragma unroll
    for (int r = 0; r < 9; ++r) {
        f4u a = *(const f4u*)(xc + r * HP);
        f4u b = *(const f4u*)(xc + r * HP + 4);
        float c = xc[r * HP + 8];
        buf[r][0] = a.x; buf[r][1] = a.y; buf[r][2] = a.z; buf[r][3] = a.w;
        buf[r][4] = b.x; buf[r][5] = b.y; buf[r][6] = b.z; buf[r][7] = b.w;
        buf[r][8] = c;
    }
}

__device__ __forceinline__ void compute_tile(const float* __restrict__ wci,
                                             const float (&buf)[9][9],
                                             float (&acc)[7][7]) {
    #pragma unroll
    for (int kh = 0; kh < 3; ++kh) {
        #pragma unroll
        for (int kw = 0; kw < 3; ++kw) {
            float wv = wci[kh * 3 + kw];   // block-uniform -> s_load
            #pragma unroll
            for (int oh = 0; oh < 7; ++oh)
                #pragma unroll
                for (int j = 0; j < 7; ++j)
                    acc[oh][j] += fabsf(buf[oh + kh][j + kw] - wv);  // 2 VALU/pair
        }
    }
}

// ---- kernel 2: main AdderNet kernel ----
// Grid: 1024 blocks = one per (n, co).  Block: 128 threads = 2 waves.
// Wave w handles ci in [w*32, w*32+32); lane = 8x8 grid of 7x7 output tiles.
// Epilogue: wave1 dumps acc to LDS, wave0 adds and stores.
// 65536 threads * 49 outputs = exact cover; 2048 waves = exactly 2/SIMD.
__global__ __launch_bounds__(128, 2) void adder_main_kernel(
    const float* __restrict__ xp, const float* __restrict__ wt,
    float* __restrict__ out) {
    __shared__ float red[64][49];   // stride 49 (odd) -> conflict-free

    int bid  = blockIdx.x;
    int n    = bid >> 6;
    int co   = bid & 63;
    int tid  = threadIdx.x;
    int wid  = tid >> 6;            // 0 or 1 (wave id)
    int lane = tid & 63;
    int tx   = lane & 7;
    int ty   = lane >> 3;
    int h0   = ty * 7;
    int w0   = tx * 7;

    const float* xbase = xp + (size_t)n * CIN_ * HPSQ + h0 * HP + w0;
    const float* wbase = wt + co * 576;   // adder[co] is contiguous (ci,kh,kw)

    float acc[7][7];
    #pragma unroll
    for (int oh = 0; oh < 7; ++oh)
        #pragma unroll
        for (int j = 0; j < 7; ++j) acc[oh][j] = 0.f;

    const int ci0 = wid * 32;
    for (int ci = ci0; ci < ci0 + 32; ++ci) {
        float buf[9][9];
        load_tile(xbase + (size_t)ci * HPSQ, buf);       // 27 VMEM, hoisted by scheduler
        compute_tile(wbase + ci * 9, buf, acc);          // 882 VALU
    }

    if (wid == 1) {
        #pragma unroll
        for (int oh = 0; oh < 7; ++oh)
            #pragma unroll
            for (int j = 0; j < 7; ++j) red[lane][oh * 7 + j] = acc[oh][j];
    }
    __syncthreads();
    if (wid == 0) {
        float* ob = out + ((size_t)(n * COUT_ + co) * HW_ + h0) * HW_ + w0;
        #pragma unroll
        for (int oh = 0; oh < 7; ++oh)
            #pragma unroll
            for (int j = 0; j < 7; ++j)
                ob[oh * HW_ + j] = -(acc[oh][j] + red[lane][oh * 7 + j]);
    }
}

extern "C" void kernel_launch(void* const* d_in, const int* in_sizes, int n_in,
                              void* d_out, int out_size, void* d_ws, size_t ws_size,
                              hipStream_t stream) {
    const float* x     = (const float*)d_in[0];
    const float* adder = (const float*)d_in[1];
    float* out = (float*)d_out;

    float* xp = (float*)d_ws;   // 16*64*58*58*4 = 13.78 MB of ws

    const int padTotal = N_ * CIN_ * HPSQ;
    pad_x_kernel<<<(padTotal + 255) / 256, 256, 0, stream>>>(x, xp);
    adder_main_kernel<<<N_ * COUT_, 128, 0, stream>>>(xp, adder, out);
}

// Round 3
// 187.842 us; speedup vs baseline: 1.1262x; 1.1262x over previous
//
#include <hip/hip_runtime.h>

#define N_    16
#define CIN_  64
#define HW_   56
#define COUT_ 64
#define HP    58            // padded H/W
#define HPSQ  (HP * HP)     // 3364

typedef float f4u __attribute__((ext_vector_type(4), aligned(4)));  // dword-aligned vec load

// ---- kernel 1: zero-padded copy of x into ws: xp[n][ci][58][58] ----
__global__ void pad_x_kernel(const float* __restrict__ x, float* __restrict__ xp) {
    int idx = blockIdx.x * 256 + threadIdx.x;
    const int total = N_ * CIN_ * HPSQ;
    if (idx >= total) return;
    int w  = idx % HP;
    int t  = idx / HP;
    int h  = t % HP;
    int nc = t / HP;
    float v = 0.f;
    if (h >= 1 && h <= HW_ && w >= 1 && w <= HW_)
        v = x[((size_t)nc * HW_ + (h - 1)) * HW_ + (w - 1)];
    xp[idx] = v;
}

// ---- kernel 2: main AdderNet kernel ----
// Grid: 1024 blocks = one per (n, co).  Block: 256 threads = 4 waves.
// Wave w handles ci in [w*16, w*16+16); lane = 8x8 grid of 7x7 output tiles.
// Rolling 3-row input window keeps live VGPRs ~95 (acc 49 + 3 rows 27 + 1
// in-flight row 9) -> no spills, unlike the all-at-once 9x9 load (81+49>128).
// 4096 waves = 4/SIMD; 4 blocks/CU co-resident (LDS 36.8KB x 4 = 150KB).
__global__ __launch_bounds__(256, 4) void adder_main_kernel(
    const float* __restrict__ xp, const float* __restrict__ wt,
    float* __restrict__ out) {
    __shared__ float red[3][64][49];   // stride 49 (odd) -> conflict-free

    int bid  = blockIdx.x;
    int n    = bid >> 6;
    int co   = bid & 63;
    int tid  = threadIdx.x;
    int wid  = tid >> 6;            // wave id 0..3
    int lane = tid & 63;
    int tx   = lane & 7;
    int ty   = lane >> 3;
    int h0   = ty * 7;
    int w0   = tx * 7;

    const float* xbase = xp + (size_t)n * CIN_ * HPSQ + h0 * HP + w0;
    const float* wbase = wt + (size_t)co * 576;   // adder[co] contiguous (ci,kh,kw)

    float acc[7][7] = {};

    const int ci0 = wid * 16;
    for (int ci = ci0; ci < ci0 + 16; ++ci) {
        const float* xc  = xbase + (size_t)ci * HPSQ;
        const float* wci = wbase + ci * 9;
        float w[9];
        #pragma unroll
        for (int k = 0; k < 9; ++k) w[k] = wci[k];   // uniform -> s_load

        float buf[9][9];
        #define LOADROW(r) { \
            f4u a_ = *(const f4u*)(xc + (r) * HP);      \
            f4u b_ = *(const f4u*)(xc + (r) * HP + 4);  \
            buf[r][0] = a_.x; buf[r][1] = a_.y; buf[r][2] = a_.z; buf[r][3] = a_.w; \
            buf[r][4] = b_.x; buf[r][5] = b_.y; buf[r][6] = b_.z; buf[r][7] = b_.w; \
            buf[r][8] = xc[(r) * HP + 8]; }
        #define COMP(oh) { \
            _Pragma("unroll") \
            for (int kh = 0; kh < 3; ++kh) { \
                _Pragma("unroll") \
                for (int kw = 0; kw < 3; ++kw) { \
                    float wv = w[kh * 3 + kw]; \
                    _Pragma("unroll") \
                    for (int j = 0; j < 7; ++j) \
                        acc[oh][j] += fabsf(buf[(oh) + kh][j + kw] - wv); \
                } } }

        // interleaved: load row (oh+2) stays >=1 compute block (~250 cyc)
        // ahead of its first use; rows older than (oh) go dead -> regalloc
        // keeps only a 3-4 row window live.
        LOADROW(0) LOADROW(1) LOADROW(2)
        COMP(0)
        LOADROW(3) COMP(1)
        LOADROW(4) COMP(2)
        LOADROW(5) COMP(3)
        LOADROW(6) COMP(4)
        LOADROW(7) COMP(5)
        LOADROW(8) COMP(6)
        #undef LOADROW
        #undef COMP
    }

    if (wid != 0) {
        float* rp = &red[wid - 1][lane][0];
        #pragma unroll
        for (int oh = 0; oh < 7; ++oh)
            #pragma unroll
            for (int j = 0; j < 7; ++j) rp[oh * 7 + j] = acc[oh][j];
    }
    __syncthreads();
    if (wid == 0) {
        float* ob = out + (((size_t)(n * COUT_ + co)) * HW_ + h0) * HW_ + w0;
        #pragma unroll
        for (int oh = 0; oh < 7; ++oh)
            #pragma unroll
            for (int j = 0; j < 7; ++j) {
                float s = acc[oh][j]
                        + red[0][lane][oh * 7 + j]
                        + red[1][lane][oh * 7 + j]
                        + red[2][lane][oh * 7 + j];
                ob[oh * HW_ + j] = -s;
            }
    }
}

extern "C" void kernel_launch(void* const* d_in, const int* in_sizes, int n_in,
                              void* d_out, int out_size, void* d_ws, size_t ws_size,
                              hipStream_t stream) {
    const float* x     = (const float*)d_in[0];
    const float* adder = (const float*)d_in[1];
    float* out = (float*)d_out;

    float* xp = (float*)d_ws;   // 16*64*58*58*4 = 13.78 MB of ws

    const int padTotal = N_ * CIN_ * HPSQ;
    pad_x_kernel<<<(padTotal + 255) / 256, 256, 0, stream>>>(x, xp);
    adder_main_kernel<<<N_ * COUT_, 256, 0, stream>>>(xp, adder, out);
}